// Round 4
// baseline (6879.588 us; speedup 1.0000x reference)
//
#include <hip/hip_runtime.h>
#include <hip/hip_cooperative_groups.h>
#include <cstdint>
#include <cstddef>

namespace cg = cooperative_groups;

// RecurrentDecoder: 128 sequential GRU steps fused via x_t = h_t @ W_dec^T
// => gates = h @ W_eff^T (4096 gate cols + 256 decode cols), one GEMM/step.
// FP32 in/out; internal GEMM fp16 MFMA; h carried fp32 (+fp16 mirror for A).
// Round 4: ONE persistent cooperative kernel for all 129 steps (grid.sync
// between steps), double-buffered one-barrier K-loop pipeline.
// 256 blocks = 8 mt x 32 cb; block tile [128 x 144], K=1024, BK=32, 4 waves.

#define HD 1024
#define BD 1024
#define OD 256
#define TS 128

typedef _Float16 f16x8 __attribute__((ext_vector_type(8)));
typedef float f32x4 __attribute__((ext_vector_type(4)));

// ---------------- prep: build W_ws [32 cb][144 rows][1024 k] fp16 ----------------
// slab row rr<128: section s=rr>>5 (0:r, 1:z, 2:i_n, 3:h_n), wcol=(rr>>4)&1, p=rr&15,
//   gate col j = cb*32 + wcol*16 + p.
//   s=0: Wc[j]+Whh[j]; s=1: Wc[1024+j]+Whh[1024+j]; s=2: Wc[2048+j]; s=3: Whh[2048+j]
// rr 128..135: W_dec row 8*cb + rr-128 ; rr 136..143: zeros.  (Wc = W_ih @ W_dec, fp32 accum)
__global__ __launch_bounds__(256) void prep_w(
    const float* __restrict__ Wih,   // [3072][256]
    const float* __restrict__ Whh,   // [3072][1024]
    const float* __restrict__ Wdec,  // [256][1024]
    _Float16* __restrict__ Wws)      // [32][144][1024]
{
  int blk = blockIdx.x, tid = threadIdx.x;
  int k0 = tid * 4;
  if (blk < 768) {                      // dot blocks: rows rr<96 (s in 0..2), 4 rows each
    int cbv[4], rrv[4], jg[4], jh[4];
    #pragma unroll
    for (int rsel = 0; rsel < 4; ++rsel) {
      int dj = blk * 4 + rsel;
      int cb = dj / 96, rr = dj % 96;
      int s = rr >> 5, wcol = (rr >> 4) & 1, p = rr & 15;
      int j = cb * 32 + wcol * 16 + p;
      cbv[rsel] = cb; rrv[rsel] = rr;
      jg[rsel] = s * 1024 + j;
      jh[rsel] = (s == 0) ? j : (s == 1 ? 1024 + j : -1);
    }
    float acc[4][4];
    #pragma unroll
    for (int a = 0; a < 4; ++a) { acc[a][0]=0.f; acc[a][1]=0.f; acc[a][2]=0.f; acc[a][3]=0.f; }
    for (int q = 0; q < 256; ++q) {
      float4 wd = *(const float4*)(Wdec + (size_t)q * 1024 + k0);
      #pragma unroll
      for (int a = 0; a < 4; ++a) {
        float w = Wih[(size_t)jg[a] * 256 + q];
        acc[a][0] += w * wd.x; acc[a][1] += w * wd.y;
        acc[a][2] += w * wd.z; acc[a][3] += w * wd.w;
      }
    }
    #pragma unroll
    for (int a = 0; a < 4; ++a) {
      if (jh[a] >= 0) {
        const float* wh = Whh + (size_t)jh[a] * 1024 + k0;
        acc[a][0] += wh[0]; acc[a][1] += wh[1];
        acc[a][2] += wh[2]; acc[a][3] += wh[3];
      }
      _Float16* dst = Wws + ((size_t)cbv[a] * 144 + rrv[a]) * 1024 + k0;
      dst[0] = (_Float16)acc[a][0]; dst[1] = (_Float16)acc[a][1];
      dst[2] = (_Float16)acc[a][2]; dst[3] = (_Float16)acc[a][3];
    }
  } else {                              // copy blocks: rows rr in 96..143
    #pragma unroll
    for (int rsel = 0; rsel < 4; ++rsel) {
      int cr = (blk - 768) * 4 + rsel;
      int cb = cr / 48, rr = 96 + cr % 48;
      _Float16* dst = Wws + ((size_t)cb * 144 + rr) * 1024 + k0;
      if (rr < 128) {                   // s=3: Whh[2048+j]
        int j = cb * 32 + ((rr >> 4) & 1) * 16 + (rr & 15);
        const float* src = Whh + (size_t)(2048 + j) * 1024 + k0;
        dst[0] = (_Float16)src[0]; dst[1] = (_Float16)src[1];
        dst[2] = (_Float16)src[2]; dst[3] = (_Float16)src[3];
      } else if (rr < 136) {
        const float* src = Wdec + (size_t)(cb * 8 + rr - 128) * 1024 + k0;
        dst[0] = (_Float16)src[0]; dst[1] = (_Float16)src[1];
        dst[2] = (_Float16)src[2]; dst[3] = (_Float16)src[3];
      } else {
        dst[0] = (_Float16)0.f; dst[1] = (_Float16)0.f;
        dst[2] = (_Float16)0.f; dst[3] = (_Float16)0.f;
      }
    }
  }
}

__global__ __launch_bounds__(256) void prep_bias(
    const float* __restrict__ Wih,
    const float* __restrict__ bih, const float* __restrict__ bhh,
    const float* __restrict__ bdec_in,
    float* __restrict__ br, float* __restrict__ bz, float* __restrict__ bin_,
    float* __restrict__ bhn, float* __restrict__ bdec)
{
  int j = blockIdx.x * 256 + threadIdx.x;   // grid 4 -> j < 1024
  float bc0 = 0.f, bc1 = 0.f, bc2 = 0.f;
  for (int q = 0; q < 256; ++q) {
    float bd = bdec_in[q];
    bc0 += Wih[(size_t)j * 256 + q] * bd;
    bc1 += Wih[(size_t)(1024 + j) * 256 + q] * bd;
    bc2 += Wih[(size_t)(2048 + j) * 256 + q] * bd;
  }
  br[j]  = bih[j]        + bhh[j]        + bc0;
  bz[j]  = bih[1024 + j] + bhh[1024 + j] + bc1;
  bin_[j]= bih[2048 + j] + bc2;
  bhn[j] = bhh[2048 + j];
  if (j < 256) bdec[j] = bdec_in[j];
}

__global__ __launch_bounds__(256) void prep_h(
    const float* __restrict__ h0, _Float16* __restrict__ h16)
{
  int i = blockIdx.x * 256 + threadIdx.x;
  h16[i] = (_Float16)h0[i];
}

// ---------------- persistent fused step kernel ----------------
// grid 256 = mt(8)*32 + cb(32); 256 thr = 4 waves (2x2 over [128x128] gates).
// Wave tile [64x64]: 4 M-frags x 4 N-frags; N-frag fn == gate section fn.
// Decode sliver [128x16]: wave w owns rows 32w..32w+31, B rows 128..143.
// K-loop: double-buffered LDS, ONE barrier/iter (store cur -> prefetch next
// -> barrier -> read cur). grid.sync() once per step carries h ping-pong.
__global__ __launch_bounds__(256, 1) void fused_steps(
    const _Float16* __restrict__ Wws,
    const float* __restrict__ br, const float* __restrict__ bz,
    const float* __restrict__ bin_, const float* __restrict__ bhn,
    const float* __restrict__ bdec,
    const float* __restrict__ h0_32,
    _Float16* __restrict__ h16A, _Float16* __restrict__ h16B,
    float* __restrict__ h32A, float* __restrict__ h32B,
    float* __restrict__ out)
{
  __shared__ __align__(16) _Float16 Asm[2][128 * 32];
  __shared__ __align__(16) _Float16 Bsm[2][144 * 32];

  cg::grid_group grid = cg::this_grid();

  const int tid = threadIdx.x;
  const int wave = tid >> 6, lane = tid & 63;
  const int mt = blockIdx.x >> 5, cb = blockIdx.x & 31;
  const int wr = wave >> 1, wc = wave & 1;
  const int col16 = lane & 15, quad = lane >> 4;

  const _Float16* __restrict__ slab = Wws + (size_t)cb * (144 * 1024);
  // 16B chunk n covers (row=n>>2, kgroup=n&3); thread handles n=tid, tid+256;
  // threads 0..63 also handle B chunks 512+tid (rows 128..143).
  const int r0 = tid >> 2, g0 = tid & 3;
  const size_t offA0 = (size_t)r0 * 1024 + g0 * 8;
  const size_t offA1 = (size_t)(r0 + 64) * 1024 + g0 * 8;
  const size_t offB2 = (size_t)(128 + r0) * 1024 + g0 * 8;

  // epilogue constants (invariant across steps)
  const int j = cb * 32 + wc * 16 + col16;       // gate col 0..1023
  const float vbr = br[j], vbz = bz[j], vbi = bin_[j], vbh = bhn[j];
  const int oc = cb * 8 + (col16 & 7);
  const float vbd = bdec[oc];

  const f32x4 fzero = {0.f, 0.f, 0.f, 0.f};

  #pragma unroll 1
  for (int t = 0; t <= TS; ++t) {
    const _Float16* __restrict__ hin16 = (t & 1) ? h16B : h16A;
    const float* __restrict__ hin32 = (t == 0) ? h0_32 : ((t & 1) ? h32B : h32A);
    _Float16* __restrict__ hout16 = (t & 1) ? h16A : h16B;
    float* __restrict__ hout32 = (t & 1) ? h32A : h32B;
    const _Float16* __restrict__ Abase = hin16 + (size_t)mt * (128 * 1024);

    f32x4 accG[4][4]; f32x4 accD[2];
    #pragma unroll
    for (int i = 0; i < 4; ++i)
      #pragma unroll
      for (int jj = 0; jj < 4; ++jj) accG[i][jj] = fzero;
    accD[0] = fzero; accD[1] = fzero;

    // prefetch chunk 0
    uint4 pa0 = *(const uint4*)(Abase + offA0);
    uint4 pa1 = *(const uint4*)(Abase + offA1);
    uint4 pb0 = *(const uint4*)(slab + offA0);
    uint4 pb1 = *(const uint4*)(slab + offA1);
    uint4 pb2 = {0, 0, 0, 0};
    if (tid < 64) pb2 = *(const uint4*)(slab + offB2);

    #pragma unroll 1
    for (int ki = 0; ki < 32; ++ki) {
      _Float16* As = Asm[ki & 1];
      _Float16* Bs = Bsm[ki & 1];
      *(uint4*)(As + (size_t)tid * 8)         = pa0;
      *(uint4*)(As + (size_t)(tid + 256) * 8) = pa1;
      *(uint4*)(Bs + (size_t)tid * 8)         = pb0;
      *(uint4*)(Bs + (size_t)(tid + 256) * 8) = pb1;
      if (tid < 64) *(uint4*)(Bs + (size_t)(512 + tid) * 8) = pb2;
      if (ki < 31) {
        const size_t kadd = (size_t)(ki + 1) * 32;
        pa0 = *(const uint4*)(Abase + offA0 + kadd);
        pa1 = *(const uint4*)(Abase + offA1 + kadd);
        pb0 = *(const uint4*)(slab + offA0 + kadd);
        pb1 = *(const uint4*)(slab + offA1 + kadd);
        if (tid < 64) pb2 = *(const uint4*)(slab + offB2 + kadd);
      }
      __syncthreads();

      f16x8 af[4], ad[2], bg[4], bdv;
      #pragma unroll
      for (int fm = 0; fm < 4; ++fm)
        af[fm] = *(const f16x8*)(As + (64 * wr + 16 * fm + col16) * 32 + quad * 8);
      #pragma unroll
      for (int d = 0; d < 2; ++d)
        ad[d] = *(const f16x8*)(As + (32 * wave + 16 * d + col16) * 32 + quad * 8);
      #pragma unroll
      for (int fn = 0; fn < 4; ++fn)
        bg[fn] = *(const f16x8*)(Bs + (32 * fn + wc * 16 + col16) * 32 + quad * 8);
      bdv = *(const f16x8*)(Bs + (128 + col16) * 32 + quad * 8);

      #pragma unroll
      for (int fm = 0; fm < 4; ++fm)
        #pragma unroll
        for (int fn = 0; fn < 4; ++fn)
          accG[fm][fn] = __builtin_amdgcn_mfma_f32_16x16x32_f16(af[fm], bg[fn], accG[fm][fn], 0, 0, 0);
      accD[0] = __builtin_amdgcn_mfma_f32_16x16x32_f16(ad[0], bdv, accD[0], 0, 0, 0);
      accD[1] = __builtin_amdgcn_mfma_f32_16x16x32_f16(ad[1], bdv, accD[1], 0, 0, 0);
    }
    // NOTE: reads of Bsm[1]@ki=31 vs next step's store@ki=1 are separated by
    // grid.sync()'s internal block barrier.

    // epilogue: gate math in registers (C/D: n = lane&15, m = quad*4 + reg)
    if (t < TS) {
      #pragma unroll
      for (int fm = 0; fm < 4; ++fm) {
        const int mbase = mt * 128 + 64 * wr + 16 * fm + quad * 4;
        #pragma unroll
        for (int ri = 0; ri < 4; ++ri) {
          const int m = mbase + ri;
          float rg = 1.f / (1.f + __expf(-(accG[fm][0][ri] + vbr)));
          float zg = 1.f / (1.f + __expf(-(accG[fm][1][ri] + vbz)));
          float nn = tanhf(accG[fm][2][ri] + vbi + rg * (accG[fm][3][ri] + vbh));
          float hold = hin32[(size_t)m * 1024 + j];
          float hnew = (1.f - zg) * nn + zg * hold;
          hout32[(size_t)m * 1024 + j] = hnew;
          hout16[(size_t)m * 1024 + j] = (_Float16)hnew;
        }
      }
    }
    if (t > 0 && col16 < 8) {          // decode of h_t -> out[:, t-1, :]
      #pragma unroll
      for (int d = 0; d < 2; ++d) {
        const int mbase = mt * 128 + 32 * wave + 16 * d + quad * 4;
        #pragma unroll
        for (int ri = 0; ri < 4; ++ri) {
          const int m = mbase + ri;
          out[(size_t)m * (TS * OD) + (size_t)(t - 1) * OD + oc] = accD[d][ri] + vbd;
        }
      }
    }

    if (t < TS) grid.sync();           // release h writes, acquire for next step
  }
}

extern "C" void kernel_launch(void* const* d_in, const int* in_sizes, int n_in,
                              void* d_out, int out_size, void* d_ws, size_t ws_size,
                              hipStream_t stream) {
  const float* h0      = (const float*)d_in[0];   // [1,1024,1024]
  const float* Wih     = (const float*)d_in[1];   // [3072,256]
  const float* Whh     = (const float*)d_in[2];   // [3072,1024]
  const float* bih     = (const float*)d_in[3];   // [3072]
  const float* bhh     = (const float*)d_in[4];   // [3072]
  const float* Wdec    = (const float*)d_in[5];   // [256,1024]
  const float* bdec_in = (const float*)d_in[6];   // [256]
  float* outp = (float*)d_out;                    // [1024,128,256] fp32

  char* ws = (char*)d_ws;
  _Float16* Wws = (_Float16*)ws;                         // 9,437,184 B
  float* br   = (float*)(ws + 9437184);
  float* bz   = (float*)(ws + 9437184 + 4096);
  float* bin_ = (float*)(ws + 9437184 + 8192);
  float* bhn  = (float*)(ws + 9437184 + 12288);
  float* bdec = (float*)(ws + 9437184 + 16384);
  float* h32A = (float*)(ws + 9461760);                  // 4 MB
  float* h32B = h32A + 1024 * 1024;                      // 4 MB
  _Float16* h16A = (_Float16*)(ws + 9461760 + 8388608);  // 2 MB
  _Float16* h16B = h16A + 1024 * 1024;                   // 2 MB
  // total ws use ~21.9 MB

  prep_w<<<1152, 256, 0, stream>>>(Wih, Whh, Wdec, Wws);
  prep_bias<<<4, 256, 0, stream>>>(Wih, bih, bhh, bdec_in, br, bz, bin_, bhn, bdec);
  prep_h<<<4096, 256, 0, stream>>>(h0, h16A);

  void* args[] = {
    (void*)&Wws, (void*)&br, (void*)&bz, (void*)&bin_, (void*)&bhn, (void*)&bdec,
    (void*)&h0, (void*)&h16A, (void*)&h16B, (void*)&h32A, (void*)&h32B, (void*)&outp
  };
  hipLaunchCooperativeKernel((const void*)fused_steps, dim3(256), dim3(256),
                             args, 0, stream);
}

// Round 6
// 2989.197 us; speedup vs baseline: 2.3015x; 2.3015x over previous
//
#include <hip/hip_runtime.h>
#include <cstdint>
#include <cstddef>

// RecurrentDecoder: 128 sequential GRU steps fused via x_t = h_t @ W_dec^T
// => gates = h @ W_eff^T (4096 gate cols + 256 decode cols), one GEMM/step.
// FP32 in/out; internal GEMM fp16 MFMA; h carried fp32 (+fp16 mirror for A).
// Round 6: R5 (async global_load_lds + dbuf BK=64 + XOR swizzle) with the
// compile fix: no LDS pointer arrays in static initializers — buffer bases
// are computed by offset arithmetic at runtime.
// 256 blocks = 8 mt x 32 cb; block tile [128 x 144], 4 waves (2x2).

#define HD 1024
#define BD 1024
#define OD 256
#define TS 128

typedef _Float16 f16x8 __attribute__((ext_vector_type(8)));
typedef float f32x4 __attribute__((ext_vector_type(4)));

__device__ __forceinline__ void gl_lds16(const void* g, void* l) {
  auto gp = reinterpret_cast<const __attribute__((address_space(1))) unsigned int*>(
      reinterpret_cast<uintptr_t>(g));
  auto lp = reinterpret_cast<__attribute__((address_space(3))) unsigned int*>(
      reinterpret_cast<uintptr_t>(l));
  __builtin_amdgcn_global_load_lds(gp, lp, 16, 0, 0);
}

// ---------------- prep: build W_ws [32 cb][144 rows][1024 k] fp16 ----------------
// slab row rr<128: section s=rr>>5 (0:r, 1:z, 2:i_n, 3:h_n), wcol=(rr>>4)&1, p=rr&15,
//   gate col j = cb*32 + wcol*16 + p.
//   s=0: Wc[j]+Whh[j]; s=1: Wc[1024+j]+Whh[1024+j]; s=2: Wc[2048+j]; s=3: Whh[2048+j]
// rr 128..135: W_dec row 8*cb + rr-128 ; rr 136..143: zeros.  (Wc = W_ih @ W_dec, fp32 accum)
__global__ __launch_bounds__(256) void prep_w(
    const float* __restrict__ Wih,   // [3072][256]
    const float* __restrict__ Whh,   // [3072][1024]
    const float* __restrict__ Wdec,  // [256][1024]
    _Float16* __restrict__ Wws)      // [32][144][1024]
{
  int blk = blockIdx.x, tid = threadIdx.x;
  int k0 = tid * 4;
  if (blk < 768) {                      // dot blocks: rows rr<96 (s in 0..2), 4 rows each
    int cbv[4], rrv[4], jg[4], jh[4];
    #pragma unroll
    for (int rsel = 0; rsel < 4; ++rsel) {
      int dj = blk * 4 + rsel;
      int cb = dj / 96, rr = dj % 96;
      int s = rr >> 5, wcol = (rr >> 4) & 1, p = rr & 15;
      int j = cb * 32 + wcol * 16 + p;
      cbv[rsel] = cb; rrv[rsel] = rr;
      jg[rsel] = s * 1024 + j;
      jh[rsel] = (s == 0) ? j : (s == 1 ? 1024 + j : -1);
    }
    float acc[4][4];
    #pragma unroll
    for (int a = 0; a < 4; ++a) { acc[a][0]=0.f; acc[a][1]=0.f; acc[a][2]=0.f; acc[a][3]=0.f; }
    for (int q = 0; q < 256; ++q) {
      float4 wd = *(const float4*)(Wdec + (size_t)q * 1024 + k0);
      #pragma unroll
      for (int a = 0; a < 4; ++a) {
        float w = Wih[(size_t)jg[a] * 256 + q];
        acc[a][0] += w * wd.x; acc[a][1] += w * wd.y;
        acc[a][2] += w * wd.z; acc[a][3] += w * wd.w;
      }
    }
    #pragma unroll
    for (int a = 0; a < 4; ++a) {
      if (jh[a] >= 0) {
        const float* wh = Whh + (size_t)jh[a] * 1024 + k0;
        acc[a][0] += wh[0]; acc[a][1] += wh[1];
        acc[a][2] += wh[2]; acc[a][3] += wh[3];
      }
      _Float16* dst = Wws + ((size_t)cbv[a] * 144 + rrv[a]) * 1024 + k0;
      dst[0] = (_Float16)acc[a][0]; dst[1] = (_Float16)acc[a][1];
      dst[2] = (_Float16)acc[a][2]; dst[3] = (_Float16)acc[a][3];
    }
  } else {                              // copy blocks: rows rr in 96..143
    #pragma unroll
    for (int rsel = 0; rsel < 4; ++rsel) {
      int cr = (blk - 768) * 4 + rsel;
      int cb = cr / 48, rr = 96 + cr % 48;
      _Float16* dst = Wws + ((size_t)cb * 144 + rr) * 1024 + k0;
      if (rr < 128) {                   // s=3: Whh[2048+j]
        int j = cb * 32 + ((rr >> 4) & 1) * 16 + (rr & 15);
        const float* src = Whh + (size_t)(2048 + j) * 1024 + k0;
        dst[0] = (_Float16)src[0]; dst[1] = (_Float16)src[1];
        dst[2] = (_Float16)src[2]; dst[3] = (_Float16)src[3];
      } else if (rr < 136) {
        const float* src = Wdec + (size_t)(cb * 8 + rr - 128) * 1024 + k0;
        dst[0] = (_Float16)src[0]; dst[1] = (_Float16)src[1];
        dst[2] = (_Float16)src[2]; dst[3] = (_Float16)src[3];
      } else {
        dst[0] = (_Float16)0.f; dst[1] = (_Float16)0.f;
        dst[2] = (_Float16)0.f; dst[3] = (_Float16)0.f;
      }
    }
  }
}

__global__ __launch_bounds__(256) void prep_bias(
    const float* __restrict__ Wih,
    const float* __restrict__ bih, const float* __restrict__ bhh,
    const float* __restrict__ bdec_in,
    float* __restrict__ br, float* __restrict__ bz, float* __restrict__ bin_,
    float* __restrict__ bhn, float* __restrict__ bdec)
{
  int j = blockIdx.x * 256 + threadIdx.x;   // grid 4 -> j < 1024
  float bc0 = 0.f, bc1 = 0.f, bc2 = 0.f;
  for (int q = 0; q < 256; ++q) {
    float bd = bdec_in[q];
    bc0 += Wih[(size_t)j * 256 + q] * bd;
    bc1 += Wih[(size_t)(1024 + j) * 256 + q] * bd;
    bc2 += Wih[(size_t)(2048 + j) * 256 + q] * bd;
  }
  br[j]  = bih[j]        + bhh[j]        + bc0;
  bz[j]  = bih[1024 + j] + bhh[1024 + j] + bc1;
  bin_[j]= bih[2048 + j] + bc2;
  bhn[j] = bhh[2048 + j];
  if (j < 256) bdec[j] = bdec_in[j];
}

__global__ __launch_bounds__(256) void prep_h(
    const float* __restrict__ h0, _Float16* __restrict__ h16)
{
  int i = blockIdx.x * 256 + threadIdx.x;
  h16[i] = (_Float16)h0[i];
}

// ---------------- step kernel ----------------
// grid 256 = mt(8)*32 + cb(32); 256 thr = 4 waves (2x2 over [128x128] gates).
// Wave tile [64x64]: 4 M-frags x 4 N-frags; N-frag fn == gate section fn.
// Decode sliver [128x16]: wave w owns rows 32w..32w+31, B rows 128..143.
// LDS: A bufs 2x16384 B then B bufs 2x18432 B. Per buffer: [row][8 kgroups
// of 16B], row stride 128 B; kgroup XOR-swizzled by (row&7), folded into the
// DMA's per-lane GLOBAL address so LDS destinations stay lane-linear.
__global__ __launch_bounds__(256, 1) void step_kernel(
    const _Float16* __restrict__ Wws,
    const float* __restrict__ br, const float* __restrict__ bz,
    const float* __restrict__ bin_, const float* __restrict__ bhn,
    const float* __restrict__ bdec,
    const _Float16* __restrict__ h_in16, const float* __restrict__ h_in32,
    _Float16* __restrict__ h_out16, float* __restrict__ h_out32,
    float* __restrict__ out, int t)
{
  __shared__ __align__(16) char lds[2 * 16384 + 2 * 18432];

  const int tid = threadIdx.x;
  const int wave = tid >> 6, lane = tid & 63;
  const int mt = blockIdx.x >> 5, cb = blockIdx.x & 31;
  const int wr = wave >> 1, wc = wave & 1;
  const int col16 = lane & 15, quad = lane >> 4;

  const _Float16* __restrict__ slab  = Wws + (size_t)cb * (144 * 1024);
  const _Float16* __restrict__ Abase = h_in16 + (size_t)mt * (128 * 1024);

  // DMA chunk geometry: chunk m (16 B) covers row r=m>>3, lds-kgroup c=m&7;
  // global kgroup g = c ^ (r&7) (swizzle). Wave w, issue j covers chunks
  // (w*4+j)*64 + lane. Extra B chunks 1024+tid (tid<128) cover rows 128..143.
  int offs[4];
  #pragma unroll
  for (int jj = 0; jj < 4; ++jj) {
    int m = (wave * 4 + jj) * 64 + lane;
    int r = m >> 3, c = m & 7, g = c ^ (r & 7);
    offs[jj] = r * 1024 + g * 8;       // element (half) offset
  }
  int offE;
  { int m = 1024 + tid; int r = m >> 3, c = m & 7, g = c ^ (r & 7);
    offE = r * 1024 + g * 8; }         // valid when tid < 128

  // ds_read swizzled column base for this lane (K-lo); K-hi = ^64 bytes
  const int swz = (quad ^ (col16 & 7)) << 4;

  f32x4 accG[4][4]; f32x4 accD[2];
  const f32x4 fzero = {0.f, 0.f, 0.f, 0.f};
  #pragma unroll
  for (int i = 0; i < 4; ++i)
    #pragma unroll
    for (int j = 0; j < 4; ++j) accG[i][j] = fzero;
  accD[0] = fzero; accD[1] = fzero;

  // ---- DMA issue for one BK=64 chunk into buffer bsel (base offsets runtime) ----
  auto issue_dma = [&](int bsel, int kc) {
    char* Ab = lds + bsel * 16384;
    char* Bb = lds + 32768 + bsel * 18432;
    #pragma unroll
    for (int jj = 0; jj < 4; ++jj) {
      gl_lds16(Abase + offs[jj] + kc, Ab + (wave * 4 + jj) * 1024);
      gl_lds16(slab  + offs[jj] + kc, Bb + (wave * 4 + jj) * 1024);
    }
    if (wave < 2)
      gl_lds16(slab + offE + kc, Bb + 16384 + wave * 1024);
  };

  issue_dma(0, 0);
  __syncthreads();                     // drains DMA(buf0)

  #pragma unroll 1
  for (int ki = 0; ki < 16; ++ki) {
    const int cur = ki & 1;
    if (ki < 15) issue_dma(cur ^ 1, (ki + 1) * 64);   // lands during MFMA phase
    const char* As = lds + cur * 16384;
    const char* Bs = lds + 32768 + cur * 18432;

    #pragma unroll
    for (int half = 0; half < 2; ++half) {
      const int sz = swz ^ (half << 6);             // column byte offset
      f16x8 af[4], ad2[2], bg[4], bdv;
      #pragma unroll
      for (int fm = 0; fm < 4; ++fm)
        af[fm] = *(const f16x8*)(As + (64 * wr + 16 * fm + col16) * 128 + sz);
      #pragma unroll
      for (int d = 0; d < 2; ++d)
        ad2[d] = *(const f16x8*)(As + (32 * wave + 16 * d + col16) * 128 + sz);
      #pragma unroll
      for (int fn = 0; fn < 4; ++fn)
        bg[fn] = *(const f16x8*)(Bs + (32 * fn + wc * 16 + col16) * 128 + sz);
      bdv = *(const f16x8*)(Bs + (128 + col16) * 128 + sz);

      #pragma unroll
      for (int fm = 0; fm < 4; ++fm)
        #pragma unroll
        for (int fn = 0; fn < 4; ++fn)
          accG[fm][fn] = __builtin_amdgcn_mfma_f32_16x16x32_f16(af[fm], bg[fn], accG[fm][fn], 0, 0, 0);
      accD[0] = __builtin_amdgcn_mfma_f32_16x16x32_f16(ad2[0], bdv, accD[0], 0, 0, 0);
      accD[1] = __builtin_amdgcn_mfma_f32_16x16x32_f16(ad2[1], bdv, accD[1], 0, 0, 0);
    }
    __syncthreads();                   // DMA for next buf drained here (overlapped)
  }

  // epilogue: gate math in registers (C/D: n = lane&15, m = quad*4 + reg)
  if (t < TS) {
    const int j = cb * 32 + wc * 16 + col16;       // gate col 0..1023
    const float vbr = br[j], vbz = bz[j], vbi = bin_[j], vbh = bhn[j];
    #pragma unroll
    for (int fm = 0; fm < 4; ++fm) {
      const int mbase = mt * 128 + 64 * wr + 16 * fm + quad * 4;
      #pragma unroll
      for (int ri = 0; ri < 4; ++ri) {
        const int m = mbase + ri;
        float rg = 1.f / (1.f + __expf(-(accG[fm][0][ri] + vbr)));
        float zg = 1.f / (1.f + __expf(-(accG[fm][1][ri] + vbz)));
        float nn = tanhf(accG[fm][2][ri] + vbi + rg * (accG[fm][3][ri] + vbh));
        float hold = h_in32[(size_t)m * 1024 + j];
        float hnew = (1.f - zg) * nn + zg * hold;
        h_out32[(size_t)m * 1024 + j] = hnew;
        h_out16[(size_t)m * 1024 + j] = (_Float16)hnew;
      }
    }
  }
  if (t > 0 && col16 < 8) {            // decode of h_t -> out[:, t-1, :]
    const int oc = cb * 8 + col16;
    const float vb = bdec[oc];
    #pragma unroll
    for (int d = 0; d < 2; ++d) {
      const int mbase = mt * 128 + 32 * wave + 16 * d + quad * 4;
      #pragma unroll
      for (int ri = 0; ri < 4; ++ri) {
        const int m = mbase + ri;
        out[(size_t)m * (TS * OD) + (size_t)(t - 1) * OD + oc] = accD[d][ri] + vb;
      }
    }
  }
}

extern "C" void kernel_launch(void* const* d_in, const int* in_sizes, int n_in,
                              void* d_out, int out_size, void* d_ws, size_t ws_size,
                              hipStream_t stream) {
  const float* h0      = (const float*)d_in[0];   // [1,1024,1024]
  const float* Wih     = (const float*)d_in[1];   // [3072,256]
  const float* Whh     = (const float*)d_in[2];   // [3072,1024]
  const float* bih     = (const float*)d_in[3];   // [3072]
  const float* bhh     = (const float*)d_in[4];   // [3072]
  const float* Wdec    = (const float*)d_in[5];   // [256,1024]
  const float* bdec_in = (const float*)d_in[6];   // [256]
  float* out = (float*)d_out;                     // [1024,128,256] fp32

  char* ws = (char*)d_ws;
  _Float16* Wws = (_Float16*)ws;                         // 9,437,184 B
  float* br   = (float*)(ws + 9437184);
  float* bz   = (float*)(ws + 9437184 + 4096);
  float* bin_ = (float*)(ws + 9437184 + 8192);
  float* bhn  = (float*)(ws + 9437184 + 12288);
  float* bdec = (float*)(ws + 9437184 + 16384);
  float* h32A = (float*)(ws + 9461760);                  // 4 MB
  float* h32B = h32A + 1024 * 1024;                      // 4 MB
  _Float16* h16A = (_Float16*)(ws + 9461760 + 8388608);  // 2 MB
  _Float16* h16B = h16A + 1024 * 1024;                   // 2 MB
  // total ws use ~21.9 MB

  prep_w<<<1152, 256, 0, stream>>>(Wih, Whh, Wdec, Wws);
  prep_bias<<<4, 256, 0, stream>>>(Wih, bih, bhh, bdec_in, br, bz, bin_, bhn, bdec);
  prep_h<<<4096, 256, 0, stream>>>(h0, h16A);

  for (int t = 0; t <= TS; ++t) {      // t=TS: decode-only pass for out[:,127,:]
    const _Float16* in16 = (t & 1) ? h16B : h16A;
    const float*    in32 = (t == 0) ? h0 : ((t & 1) ? h32B : h32A);
    _Float16*       o16  = (t & 1) ? h16A : h16B;
    float*          o32  = (t & 1) ? h32A : h32B;
    step_kernel<<<256, 256, 0, stream>>>(Wws, br, bz, bin_, bhn, bdec,
                                         in16, in32, o16, o32, out, t);
  }
}